// Round 12
// baseline (301.119 us; speedup 1.0000x reference)
//
#include <hip/hip_runtime.h>

#define Bb 8
#define Nn 1025
#define Hh 12
#define HD 64
#define DIMC 768
#define QKVC 2304          // 3*DIMC, token stride of packed qkv
#define MROWS (Bb * Nn)    // 8200
#define MPADA 8320         // 65*128, padded A rows for unguarded global_load_lds staging
#define NPAD 1152          // 9*128, zero-padded token dim for transposed V
#define K1 0.180336880111f // 0.125 * log2(e) — folded into q by rope kernel
#define PADCNT 127.0f      // pad tokens, each contributing p=2^0=1 to l
#define RBLK ((Bb * Hh * Nn + 3) / 4)   // rope BLOCKS: 98400 waves / 4 per block = 24600
#define VTBLK ((NPAD / 128) * Bb * Hh)  // vtrans blocks: 9 * 96 = 864

typedef _Float16 f16x8 __attribute__((ext_vector_type(8)));
typedef _Float16 f16x4 __attribute__((ext_vector_type(4)));
typedef float f32x4 __attribute__((ext_vector_type(4)));

typedef const __attribute__((address_space(1))) void gv_t;
typedef __attribute__((address_space(3))) void lv_t;

// ---------------- fused fp32 -> fp16 convert for 3 tensors ----------------
__global__ void cvt3_kernel(const float* __restrict__ s0, _Float16* __restrict__ d0, int n0,
                            const float* __restrict__ s1, _Float16* __restrict__ d1, int n1,
                            const float* __restrict__ s2, _Float16* __restrict__ d2, int n2) {
    int i = blockIdx.x * 256 + threadIdx.x;
    const float* s; _Float16* d; int j;
    if (i < n0)           { s = s0; d = d0; j = i; }
    else if (i < n0 + n1) { s = s1; d = d1; j = i - n0; }
    else if (i < n0 + n1 + n2) { s = s2; d = d2; j = i - n0 - n1; }
    else return;
    float4 v = ((const float4*)s)[j];
    f16x4 h;
    h.x = (_Float16)v.x; h.y = (_Float16)v.y; h.z = (_Float16)v.z; h.w = (_Float16)v.w;
    ((f16x4*)d)[j] = h;
}

// ---------------- MFMA GEMM, global_load_lds staging, 2xBK=32 per barrier ----------------
template <int MODE>
__global__ void __launch_bounds__(256) gemm_kernel(
    const _Float16* __restrict__ A, const _Float16* __restrict__ W,
    int M, int Ncols, int K,
    _Float16* __restrict__ outh, const float* __restrict__ bias, float* __restrict__ outf)
{
    __shared__ _Float16 As[2][128 * 32];
    __shared__ _Float16 Ws[2][128 * 32];
    const int tid = threadIdx.x;
    const int wid = tid >> 6, lane = tid & 63;
    const int quad = lane >> 4, l16 = lane & 15;
    const int bm = blockIdx.x * 128, bn = blockIdx.y * 128;
    const int wm = (wid >> 1) * 64, wn = (wid & 1) * 64;

    f32x4 acc[4][4] = {};

    for (int kk = 0; kk < K; kk += 64) {
#pragma unroll
        for (int half = 0; half < 2; ++half) {
#pragma unroll
            for (int c = 0; c < 2; ++c) {
                int s = c * 256 + tid;
                int row = s >> 2, gr = s & 3;
                const _Float16* ga = A + (size_t)(bm + row) * K + kk + half * 32 + gr * 8;
                const _Float16* gw = W + (size_t)(bn + row) * K + kk + half * 32 + gr * 8;
                _Float16* la = As[half] + (size_t)(c * 256 + wid * 64) * 8;
                _Float16* lw = Ws[half] + (size_t)(c * 256 + wid * 64) * 8;
                __builtin_amdgcn_global_load_lds((gv_t*)ga, (lv_t*)la, 16, 0, 0);
                __builtin_amdgcn_global_load_lds((gv_t*)gw, (lv_t*)lw, 16, 0, 0);
            }
        }
        __syncthreads();

#pragma unroll
        for (int half = 0; half < 2; ++half) {
            f16x8 af[4], bf[4];
#pragma unroll
            for (int t = 0; t < 4; ++t) {
                af[t] = *(const f16x8*)(As[half] + (size_t)(wm + t * 16 + l16) * 32 + quad * 8);
                bf[t] = *(const f16x8*)(Ws[half] + (size_t)(wn + t * 16 + l16) * 32 + quad * 8);
            }
#pragma unroll
            for (int tm = 0; tm < 4; ++tm)
#pragma unroll
                for (int tn = 0; tn < 4; ++tn)
                    acc[tm][tn] = __builtin_amdgcn_mfma_f32_16x16x32_f16(af[tm], bf[tn], acc[tm][tn], 0, 0, 0);
        }
        __syncthreads();
    }

#pragma unroll
    for (int tm = 0; tm < 4; ++tm) {
#pragma unroll
        for (int r = 0; r < 4; ++r) {
            int row = bm + wm + tm * 16 + quad * 4 + r;
            if (row >= M) continue;
#pragma unroll
            for (int tn = 0; tn < 4; ++tn) {
                int col = bn + wn + tn * 16 + l16;
                float val = acc[tm][tn][r];
                if (MODE == 0) {
                    outh[(size_t)row * Ncols + col] = (_Float16)val;
                } else {
                    outf[(size_t)row * Ncols + col] = val + bias[col];
                }
            }
        }
    }
}

// ---------------- fused RoPE-2D (+scale-fold, cls dots) and permuted V-transpose ----------------
// Blocks [0, RBLK): rope on q/k slices (4 waves/block, one (b,h,n) each).
// Blocks [RBLK, RBLK+VTBLK): vtrans on v slice, 128-token tiles, PERMUTED token
// order within each chunk: vt position c holds token tau(c) = (c&7)*16 + (c>>3).
// This makes flash's Ps writes contiguous (see flash comment). Disjoint data.
__global__ void __launch_bounds__(256) ropevtrans_kernel(
    _Float16* __restrict__ qkv, const int* __restrict__ xpos,
    float* __restrict__ col0, float* __restrict__ row0, _Float16* __restrict__ vt)
{
    __shared__ _Float16 Ts[128][72];
    const int blk = blockIdx.x;
    const int tid = threadIdx.x;

    if (blk < RBLK) {
        // ---- rope part: one wave per (b,h,n) ----
        int gw = blk * 4 + (tid >> 6);
        int lane = tid & 63;
        if (gw >= Bb * Hh * Nn) return;
        int n = gw % Nn;
        int bh = gw / Nn;
        int b = bh / Hh, h = bh - b * Hh;

        _Float16* qp = qkv + ((size_t)b * Nn + n) * QKVC + h * HD;
        _Float16* kp = qp + DIMC;
        const _Float16* qp0 = qkv + (size_t)b * Nn * QKVC + h * HD;
        const _Float16* kp0 = qp0 + DIMC;

        float q = (float)qp[lane];
        float k = (float)kp[lane];
        float q0 = (float)qp0[lane];
        float k0 = (float)kp0[lane];

        float dcol = q * k0, drow = q0 * k;
#pragma unroll
        for (int off = 1; off < 64; off <<= 1) {
            dcol += __shfl_xor(dcol, off);
            drow += __shfl_xor(drow, off);
        }
        if (lane == 0) {
            col0[gw] = dcol * K1;   // pre-scaled: flash does p = exp2(value)
            row0[gw] = drow * K1;
        }

        if (n >= 1) {
            int py = xpos[((size_t)b * Nn + n) * 2 + 0];
            int px = xpos[((size_t)b * Nn + n) * 2 + 1];
            float pos = (lane < 32) ? (float)py : (float)px;
            int j = lane & 15;
            float inv = __expf(-0.28782313662f * (float)j);   // 100^(-j/16)
            float ang = pos * inv;
            float sv = __sinf(ang), cv = __cosf(ang);
            float qp_ = __shfl_xor(q, 16);
            float kp_ = __shfl_xor(k, 16);
            float sgn = (lane & 16) ? 1.0f : -1.0f;
            qp[lane] = (_Float16)((q * cv + sgn * qp_ * sv) * K1);   // scale folded into q
            kp[lane] = (_Float16)(k * cv + sgn * kp_ * sv);          // k unscaled
        }
    } else {
        // ---- vtrans part: 128-token chunk, permuted columns ----
        int idx = blk - RBLK;
        int nt = idx % (NPAD / 128);     // 0..8
        int bh = idx / (NPAD / 128);
        int b = bh / Hh, h = bh - b * Hh;
        int c0 = nt * 128;
        const _Float16* vsrc = qkv + (size_t)b * Nn * QKVC + 2 * DIMC + h * HD;
#pragma unroll
        for (int i = 0; i < 4; ++i) {
            int t = tid + i * 256;
            int r = t >> 3, cg = t & 7;   // token-in-chunk, 16B group
            int gn = c0 + r;
            f16x8 v8 = {};
            if (gn < Nn) v8 = *(const f16x8*)(vsrc + (size_t)gn * QKVC + cg * 8);
            *(f16x8*)&Ts[r][cg * 8] = v8;
        }
        __syncthreads();
#pragma unroll
        for (int i = 0; i < 4; ++i) {
            int t = tid + i * 256;
            int d = t >> 4, pg = t & 15;  // feature, position-group
            f16x8 o;
#pragma unroll
            for (int j = 0; j < 8; ++j) o[j] = Ts[j * 16 + pg][d];   // token tau(pg*8+j)
            *(f16x8*)(vt + ((size_t)bh * HD + d) * NPAD + c0 + pg * 8) = o;
        }
    }
}

// ---------------- flash attention: permuted-P layout, vectorized Ps writes ----------------
// R8 structure + token-permutation: P value for token t goes to Ps column
// pi(t) = (t&15)*8 + (t>>4) (per 128-chunk), so each lane's 8 values per r are
// CONTIGUOUS -> 4 ds_write_b128 instead of 32 ds_write_b16 per chunk (the Ps
// scalar writes were ~23% of the LDS-pipe budget). vt is stored in the same
// permuted order (ropevtrans), so the PV MFMA sums over identically-permuted
// positions — softmax/PV invariant. S-space cls overrides & pad accounting
// unchanged. Fragment operands from LDS only (R6); no bpermute (R9); plain
// launch_bounds(256) (min-waves spilled, R2/R3).
__global__ void __launch_bounds__(256) flash_kernel(
    const _Float16* __restrict__ qkv, const _Float16* __restrict__ vt,
    const float* __restrict__ col0, const float* __restrict__ row0,
    _Float16* __restrict__ att)
{
    __shared__ _Float16 Ks[128][72];
    __shared__ _Float16 Vt[64][136];
    __shared__ _Float16 Ps[64][136];   // wave-private rows

    const int qt = blockIdx.x, bh = blockIdx.y;
    const int b = bh / Hh, h = bh - b * Hh;
    const int tid = threadIdx.x, wid = tid >> 6, lane = tid & 63;
    const int quad = lane >> 4, l16 = lane & 15;
    const int q0row = qt * 64;
    const int c0base = bh * Nn;
    const _Float16* qg = qkv + (size_t)b * Nn * QKVC + h * HD;   // + n*QKVC + d
    const _Float16* kg = qg + DIMC;
    const _Float16* vtg = vt + (size_t)bh * HD * NPAD;

    // staging coordinates (fixed per thread)
    const int kR = tid >> 3, kC = (tid & 7) * 8;    // K: rows kR + i*32
    const int vD = tid >> 4, vC = (tid & 15) * 8;   // V: rows vD + i*16

    // stage Q tile into Ks rows 0..63, hoist fragments, release the buffer
#pragma unroll
    for (int i = 0; i < 2; ++i) {
        int t = tid + i * 256;
        int r = t >> 3, cg = t & 7;
        int gr = q0row + r;
        f16x8 v8 = {};
        if (gr < Nn) v8 = *(const f16x8*)(qg + (size_t)gr * QKVC + cg * 8);
        *(f16x8*)&Ks[r][cg * 8] = v8;
    }
    __syncthreads();
    f16x8 aq[2];
#pragma unroll
    for (int ks = 0; ks < 2; ++ks)
        aq[ks] = *(const f16x8*)&Ks[wid * 16 + l16][ks * 32 + quad * 8];
    __syncthreads();

    f32x4 oacc[4] = {};
    float lrow[4] = {0.f, 0.f, 0.f, 0.f};
    const int gibase = q0row + wid * 16 + quad * 4;

    // prefetch chunk 0 into registers
    f16x8 kreg[4], vreg[4];
#pragma unroll
    for (int i = 0; i < 4; ++i) {
        int gr = kR + i * 32;
        f16x8 v8 = {};
        if (gr < Nn) v8 = *(const f16x8*)(kg + (size_t)gr * QKVC + kC);
        kreg[i] = v8;
        vreg[i] = *(const f16x8*)(vtg + (size_t)(vD + i * 16) * NPAD + vC);
    }

    for (int c0 = 0; c0 < Nn; c0 += 128) {
        // commit prefetched registers to LDS
#pragma unroll
        for (int i = 0; i < 4; ++i) {
            *(f16x8*)&Ks[kR + i * 32][kC] = kreg[i];
            *(f16x8*)&Vt[vD + i * 16][vC] = vreg[i];
        }
        __syncthreads();

        // prefetch next chunk (VMEM overlapped with compute below)
        int cn = c0 + 128;
        if (cn < Nn) {
#pragma unroll
            for (int i = 0; i < 4; ++i) {
                int gr = cn + kR + i * 32;
                f16x8 v8 = {};
                if (gr < Nn) v8 = *(const f16x8*)(kg + (size_t)gr * QKVC + kC);
                kreg[i] = v8;
                vreg[i] = *(const f16x8*)(vtg + (size_t)(vD + i * 16) * NPAD + cn + vC);
            }
        }

        // S' = Q' K^T  (scale already folded into Q)
        f32x4 sacc[8] = {};
#pragma unroll
        for (int ks = 0; ks < 2; ++ks)
#pragma unroll
            for (int ct = 0; ct < 8; ++ct) {
                f16x8 bk = *(const f16x8*)&Ks[ct * 16 + l16][ks * 32 + quad * 8];
                sacc[ct] = __builtin_amdgcn_mfma_f32_16x16x32_f16(aq[ks], bk, sacc[ct], 0, 0, 0);
            }

        // cls column (gj==0): only chunk 0
        if (c0 == 0 && l16 == 0) {
#pragma unroll
            for (int r = 0; r < 4; ++r) {
                int gi = gibase + r;
                sacc[0][r] = col0[c0base + (gi < Nn ? gi : 0)];
            }
        }
        // cls row (gi==0): only first q-tile, wave 0, quad 0
        if (q0row == 0 && wid == 0 && quad == 0) {
#pragma unroll
            for (int ct = 0; ct < 8; ++ct) {
                int gj = c0 + ct * 16 + l16;
                if (gj < Nn) sacc[ct][0] = row0[c0base + gj];
            }
        }

        // p = 2^s'; partial row sums; Ps write at permuted col pi(token) =
        // l16*8 + ct -> one b128 per r. Pad cols: p=1, corrected by -PADCNT.
#pragma unroll
        for (int r = 0; r < 4; ++r) {
            f16x8 w;
#pragma unroll
            for (int ct = 0; ct < 8; ++ct) {
                float p = exp2f(sacc[ct][r]);
                lrow[r] += p;
                w[ct] = (_Float16)p;
            }
            *(f16x8*)&Ps[wid * 16 + quad * 4 + r][l16 * 8] = w;
        }

        // O += P @ V  (own Ps rows + shared Vt; both in permuted position space)
#pragma unroll
        for (int ks = 0; ks < 4; ++ks) {
            f16x8 ap = *(const f16x8*)&Ps[wid * 16 + l16][ks * 32 + quad * 8];
#pragma unroll
            for (int ct = 0; ct < 4; ++ct) {
                f16x8 bv = *(const f16x8*)&Vt[ct * 16 + l16][ks * 32 + quad * 8];
                oacc[ct] = __builtin_amdgcn_mfma_f32_16x16x32_f16(ap, bv, oacc[ct], 0, 0, 0);
            }
        }
        __syncthreads();   // Ks/Vt consumed before next chunk's commit
    }

    // epilogue: 16-lane reduce of l, subtract pad contribution, store att
#pragma unroll
    for (int r = 0; r < 4; ++r) {
        float l = lrow[r];
#pragma unroll
        for (int off = 1; off < 16; off <<= 1) l += __shfl_xor(l, off);
        l -= PADCNT;
        int gi = q0row + wid * 16 + quad * 4 + r;
        if (gi >= Nn) continue;
        float inv_l = 1.0f / l;
#pragma unroll
        for (int ct = 0; ct < 4; ++ct) {
            att[((size_t)b * Nn + gi) * DIMC + h * HD + ct * 16 + l16] =
                (_Float16)(oacc[ct][r] * inv_l);
        }
    }
}

extern "C" void kernel_launch(void* const* d_in, const int* in_sizes, int n_in,
                              void* d_out, int out_size, void* d_ws, size_t ws_size,
                              hipStream_t stream) {
    const float* x      = (const float*)d_in[1];
    const int*   xpos   = (const int*)d_in[2];
    const float* w_qkv  = (const float*)d_in[4];
    const float* w_proj = (const float*)d_in[5];
    const float* b_proj = (const float*)d_in[6];
    float* out = (float*)d_out;

    char* ws = (char*)d_ws;
    size_t off = 0;
    auto alloc = [&](size_t bytes) {
        char* p = ws + off;
        off += (bytes + 255) & ~(size_t)255;
        return p;
    };
    _Float16* xh     = (_Float16*)alloc((size_t)MPADA * DIMC * 2);   // padded rows for unguarded staging
    _Float16* qkvh   = (_Float16*)alloc((size_t)MROWS * QKVC * 2);
    _Float16* vt     = (_Float16*)alloc((size_t)Bb * Hh * HD * NPAD * 2);
    _Float16* wqkvh  = (_Float16*)alloc((size_t)3 * DIMC * DIMC * 2);
    _Float16* wprojh = (_Float16*)alloc((size_t)DIMC * DIMC * 2);
    float* col0      = (float*)alloc((size_t)Bb * Hh * Nn * 4);
    float* row0      = (float*)alloc((size_t)Bb * Hh * Nn * 4);
    _Float16* atth   = xh;  // alias: x consumed by QKV GEMM before flash writes att

    {
        int n0 = (MROWS * DIMC) / 4;
        int n1 = (3 * DIMC * DIMC) / 4;
        int n2 = (DIMC * DIMC) / 4;
        int nt = n0 + n1 + n2;
        cvt3_kernel<<<(nt + 255) / 256, 256, 0, stream>>>(
            x, xh, n0, w_qkv, wqkvh, n1, w_proj, wprojh, n2);
    }

    // QKV projection -> packed [b,n,3,h,d] (natural GEMM C layout)
    gemm_kernel<0><<<dim3(MPADA / 128, QKVC / 128), 256, 0, stream>>>(
        xh, wqkvh, MROWS, QKVC, DIMC, qkvh, nullptr, nullptr);

    // fused rope (q/k) + permuted V transpose
    ropevtrans_kernel<<<RBLK + VTBLK, 256, 0, stream>>>(
        qkvh, xpos, col0, row0, vt);

    flash_kernel<<<dim3((Nn + 63) / 64, Bb * Hh), 256, 0, stream>>>(
        qkvh, vt, col0, row0, atth);

    gemm_kernel<1><<<dim3(MPADA / 128, DIMC / 128), 256, 0, stream>>>(
        atth, wprojh, MROWS, DIMC, DIMC, nullptr, b_proj, out);
}

// Round 13
// 282.098 us; speedup vs baseline: 1.0674x; 1.0674x over previous
//
#include <hip/hip_runtime.h>

#define Bb 8
#define Nn 1025
#define Hh 12
#define HD 64
#define DIMC 768
#define QKVC 2304          // 3*DIMC, token stride of packed qkv
#define MROWS (Bb * Nn)    // 8200
#define MPADA 8320         // 65*128, padded A rows for unguarded global_load_lds staging
#define VNP 1024           // transposed-V token dim: exactly 8 chunks of 128
#define K1 0.180336880111f // 0.125 * log2(e) — folded into q by rope kernel
#define RBLK ((Bb * Hh * Nn + 3) / 4)   // rope BLOCKS: 98400 waves / 4 per block = 24600
#define VTBLK ((VNP / 64) * Bb * Hh)    // vtrans blocks: 16 * 96 = 1536

typedef _Float16 f16x8 __attribute__((ext_vector_type(8)));
typedef _Float16 f16x4 __attribute__((ext_vector_type(4)));
typedef float f32x4 __attribute__((ext_vector_type(4)));

typedef const __attribute__((address_space(1))) void gv_t;
typedef __attribute__((address_space(3))) void lv_t;

// ---------------- fused fp32 -> fp16 convert for 3 tensors ----------------
__global__ void cvt3_kernel(const float* __restrict__ s0, _Float16* __restrict__ d0, int n0,
                            const float* __restrict__ s1, _Float16* __restrict__ d1, int n1,
                            const float* __restrict__ s2, _Float16* __restrict__ d2, int n2) {
    int i = blockIdx.x * 256 + threadIdx.x;
    const float* s; _Float16* d; int j;
    if (i < n0)           { s = s0; d = d0; j = i; }
    else if (i < n0 + n1) { s = s1; d = d1; j = i - n0; }
    else if (i < n0 + n1 + n2) { s = s2; d = d2; j = i - n0 - n1; }
    else return;
    float4 v = ((const float4*)s)[j];
    f16x4 h;
    h.x = (_Float16)v.x; h.y = (_Float16)v.y; h.z = (_Float16)v.z; h.w = (_Float16)v.w;
    ((f16x4*)d)[j] = h;
}

// ---------------- MFMA GEMM, global_load_lds staging, 2xBK=32 per barrier ----------------
template <int MODE>
__global__ void __launch_bounds__(256) gemm_kernel(
    const _Float16* __restrict__ A, const _Float16* __restrict__ W,
    int M, int Ncols, int K,
    _Float16* __restrict__ outh, const float* __restrict__ bias, float* __restrict__ outf)
{
    __shared__ _Float16 As[2][128 * 32];
    __shared__ _Float16 Ws[2][128 * 32];
    const int tid = threadIdx.x;
    const int wid = tid >> 6, lane = tid & 63;
    const int quad = lane >> 4, l16 = lane & 15;
    const int bm = blockIdx.x * 128, bn = blockIdx.y * 128;
    const int wm = (wid >> 1) * 64, wn = (wid & 1) * 64;

    f32x4 acc[4][4] = {};

    for (int kk = 0; kk < K; kk += 64) {
#pragma unroll
        for (int half = 0; half < 2; ++half) {
#pragma unroll
            for (int c = 0; c < 2; ++c) {
                int s = c * 256 + tid;
                int row = s >> 2, gr = s & 3;
                const _Float16* ga = A + (size_t)(bm + row) * K + kk + half * 32 + gr * 8;
                const _Float16* gw = W + (size_t)(bn + row) * K + kk + half * 32 + gr * 8;
                _Float16* la = As[half] + (size_t)(c * 256 + wid * 64) * 8;
                _Float16* lw = Ws[half] + (size_t)(c * 256 + wid * 64) * 8;
                __builtin_amdgcn_global_load_lds((gv_t*)ga, (lv_t*)la, 16, 0, 0);
                __builtin_amdgcn_global_load_lds((gv_t*)gw, (lv_t*)lw, 16, 0, 0);
            }
        }
        __syncthreads();

#pragma unroll
        for (int half = 0; half < 2; ++half) {
            f16x8 af[4], bf[4];
#pragma unroll
            for (int t = 0; t < 4; ++t) {
                af[t] = *(const f16x8*)(As[half] + (size_t)(wm + t * 16 + l16) * 32 + quad * 8);
                bf[t] = *(const f16x8*)(Ws[half] + (size_t)(wn + t * 16 + l16) * 32 + quad * 8);
            }
#pragma unroll
            for (int tm = 0; tm < 4; ++tm)
#pragma unroll
                for (int tn = 0; tn < 4; ++tn)
                    acc[tm][tn] = __builtin_amdgcn_mfma_f32_16x16x32_f16(af[tm], bf[tn], acc[tm][tn], 0, 0, 0);
        }
        __syncthreads();
    }

#pragma unroll
    for (int tm = 0; tm < 4; ++tm) {
#pragma unroll
        for (int r = 0; r < 4; ++r) {
            int row = bm + wm + tm * 16 + quad * 4 + r;
            if (row >= M) continue;
#pragma unroll
            for (int tn = 0; tn < 4; ++tn) {
                int col = bn + wn + tn * 16 + l16;
                float val = acc[tm][tn][r];
                if (MODE == 0) {
                    outh[(size_t)row * Ncols + col] = (_Float16)val;
                } else {
                    outf[(size_t)row * Ncols + col] = val + bias[col];
                }
            }
        }
    }
}

// ---------------- fused RoPE-2D (+scale-fold, cls dots) and V-transpose ----------------
// Blocks [0, RBLK): rope on q/k slices (4 waves/block, one (b,h,n) each).
// Blocks [RBLK, RBLK+VTBLK): vtrans tokens 0..1023 -> vt[bh][64][VNP] (token 1024
// is handled by flash's rank-1 epilogue and never enters vt). Disjoint data.
__global__ void __launch_bounds__(256) ropevtrans_kernel(
    _Float16* __restrict__ qkv, const int* __restrict__ xpos,
    float* __restrict__ col0, float* __restrict__ row0, _Float16* __restrict__ vt)
{
    __shared__ _Float16 Ts[64][72];
    const int blk = blockIdx.x;
    const int tid = threadIdx.x;

    if (blk < RBLK) {
        // ---- rope part: one wave per (b,h,n) ----
        int gw = blk * 4 + (tid >> 6);
        int lane = tid & 63;
        if (gw >= Bb * Hh * Nn) return;
        int n = gw % Nn;
        int bh = gw / Nn;
        int b = bh / Hh, h = bh - b * Hh;

        _Float16* qp = qkv + ((size_t)b * Nn + n) * QKVC + h * HD;
        _Float16* kp = qp + DIMC;
        const _Float16* qp0 = qkv + (size_t)b * Nn * QKVC + h * HD;
        const _Float16* kp0 = qp0 + DIMC;

        float q = (float)qp[lane];
        float k = (float)kp[lane];
        float q0 = (float)qp0[lane];
        float k0 = (float)kp0[lane];

        float dcol = q * k0, drow = q0 * k;
#pragma unroll
        for (int off = 1; off < 64; off <<= 1) {
            dcol += __shfl_xor(dcol, off);
            drow += __shfl_xor(drow, off);
        }
        if (lane == 0) {
            col0[gw] = dcol * K1;   // pre-scaled: flash does p = exp2(value)
            row0[gw] = drow * K1;
        }

        if (n >= 1) {
            int py = xpos[((size_t)b * Nn + n) * 2 + 0];
            int px = xpos[((size_t)b * Nn + n) * 2 + 1];
            float pos = (lane < 32) ? (float)py : (float)px;
            int j = lane & 15;
            float inv = __expf(-0.28782313662f * (float)j);   // 100^(-j/16)
            float ang = pos * inv;
            float sv = __sinf(ang), cv = __cosf(ang);
            float qp_ = __shfl_xor(q, 16);
            float kp_ = __shfl_xor(k, 16);
            float sgn = (lane & 16) ? 1.0f : -1.0f;
            qp[lane] = (_Float16)((q * cv + sgn * qp_ * sv) * K1);   // scale folded into q
            kp[lane] = (_Float16)(k * cv + sgn * kp_ * sv);          // k unscaled
        }
    } else {
        // ---- vtrans part: qkv v-slice (tokens 0..1023) -> vt[bh][64][VNP] ----
        int idx = blk - RBLK;
        int nt = idx % (VNP / 64);
        int bh = idx / (VNP / 64);
        int b = bh / Hh, h = bh - b * Hh;
        int n0 = nt * 64;
        const _Float16* vsrc = qkv + (size_t)b * Nn * QKVC + 2 * DIMC + h * HD;
#pragma unroll
        for (int i = 0; i < 2; ++i) {
            int t = tid + i * 256;
            int r = t >> 3, cg = t & 7;
            f16x8 v8 = *(const f16x8*)(vsrc + (size_t)(n0 + r) * QKVC + cg * 8);
            *(f16x8*)&Ts[r][cg * 8] = v8;
        }
        __syncthreads();
#pragma unroll
        for (int i = 0; i < 2; ++i) {
            int t = tid + i * 256;
            int d = t >> 3, ng = t & 7;
            f16x8 o;
#pragma unroll
            for (int s = 0; s < 8; ++s) o[s] = Ts[ng * 8 + s][d];
            *(f16x8*)(vt + ((size_t)bh * HD + d) * VNP + n0 + ng * 8) = o;
        }
    }
}

// ---------------- flash attention: R11 body, 8 exact chunks + rank-1 token-1024 ----------------
// N=1025 = 8*128 + 1: the 9th chunk used to compute 128 cols to use 1 (~11% of the
// kernel). Now 8 unguarded chunks cover tokens 0..1023; token 1024 is a rank-1
// epilogue: per-lane dot from the hoisted aq fragments + quad reduce -> p, predicated
// lrow add (owner lane quad==l16>>4's slot), 4 shfl + 16 fma O update. l is exact
// (no pad correction). Fragment operands from LDS only (R6); no bpermute (R9); no
// pack-before-write (R12); plain launch_bounds(256) (min-waves spilled, R2/R3).
__global__ void __launch_bounds__(256) flash_kernel(
    const _Float16* __restrict__ qkv, const _Float16* __restrict__ vt,
    const float* __restrict__ col0, const float* __restrict__ row0,
    _Float16* __restrict__ att)
{
    __shared__ _Float16 Ks[128][72];
    __shared__ _Float16 Vt[64][136];
    __shared__ _Float16 Ps[64][136];   // wave-private rows

    const int qt = blockIdx.x, bh = blockIdx.y;
    const int b = bh / Hh, h = bh - b * Hh;
    const int tid = threadIdx.x, wid = tid >> 6, lane = tid & 63;
    const int quad = lane >> 4, l16 = lane & 15;
    const int q0row = qt * 64;
    const int c0base = bh * Nn;
    const _Float16* qg = qkv + (size_t)b * Nn * QKVC + h * HD;   // + n*QKVC + d
    const _Float16* kg = qg + DIMC;
    const _Float16* vtg = vt + (size_t)bh * HD * VNP;

    // staging coordinates (fixed per thread)
    const int kR = tid >> 3, kC = (tid & 7) * 8;    // K: rows kR + i*32
    const int vD = tid >> 4, vC = (tid & 15) * 8;   // V: rows vD + i*16

    // stage Q tile into Ks rows 0..63, hoist fragments, release the buffer
#pragma unroll
    for (int i = 0; i < 2; ++i) {
        int t = tid + i * 256;
        int r = t >> 3, cg = t & 7;
        int gr = q0row + r;
        f16x8 v8 = {};
        if (gr < Nn) v8 = *(const f16x8*)(qg + (size_t)gr * QKVC + cg * 8);
        *(f16x8*)&Ks[r][cg * 8] = v8;
    }
    __syncthreads();
    f16x8 aq[2];
#pragma unroll
    for (int ks = 0; ks < 2; ++ks)
        aq[ks] = *(const f16x8*)&Ks[wid * 16 + l16][ks * 32 + quad * 8];
    __syncthreads();

    f32x4 oacc[4] = {};
    float lrow[4] = {0.f, 0.f, 0.f, 0.f};
    const int gibase = q0row + wid * 16 + quad * 4;

    // prefetch chunk 0 into registers (rows 0..127 all valid -> no guards)
    f16x8 kreg[4], vreg[4];
#pragma unroll
    for (int i = 0; i < 4; ++i) {
        kreg[i] = *(const f16x8*)(kg + (size_t)(kR + i * 32) * QKVC + kC);
        vreg[i] = *(const f16x8*)(vtg + (size_t)(vD + i * 16) * VNP + vC);
    }

    for (int c0 = 0; c0 < VNP; c0 += 128) {
        // commit prefetched registers to LDS
#pragma unroll
        for (int i = 0; i < 4; ++i) {
            *(f16x8*)&Ks[kR + i * 32][kC] = kreg[i];
            *(f16x8*)&Vt[vD + i * 16][vC] = vreg[i];
        }
        __syncthreads();

        // prefetch next chunk (rows <= 1023, unguarded; overlapped with compute)
        int cn = c0 + 128;
        if (cn < VNP) {
#pragma unroll
            for (int i = 0; i < 4; ++i) {
                kreg[i] = *(const f16x8*)(kg + (size_t)(cn + kR + i * 32) * QKVC + kC);
                vreg[i] = *(const f16x8*)(vtg + (size_t)(vD + i * 16) * VNP + cn + vC);
            }
        }

        // S' = Q' K^T  (scale already folded into Q)
        f32x4 sacc[8] = {};
#pragma unroll
        for (int ks = 0; ks < 2; ++ks)
#pragma unroll
            for (int ct = 0; ct < 8; ++ct) {
                f16x8 bk = *(const f16x8*)&Ks[ct * 16 + l16][ks * 32 + quad * 8];
                sacc[ct] = __builtin_amdgcn_mfma_f32_16x16x32_f16(aq[ks], bk, sacc[ct], 0, 0, 0);
            }

        // cls column (gj==0): only chunk 0
        if (c0 == 0 && l16 == 0) {
#pragma unroll
            for (int r = 0; r < 4; ++r) {
                int gi = gibase + r;
                sacc[0][r] = col0[c0base + (gi < Nn ? gi : 0)];
            }
        }
        // cls row (gi==0): only first q-tile, wave 0, quad 0
        if (q0row == 0 && wid == 0 && quad == 0) {
#pragma unroll
            for (int ct = 0; ct < 8; ++ct)
                sacc[ct][0] = row0[c0base + c0 + ct * 16 + l16];
        }

        // p = 2^s'; partial row sums; stage to Ps (f16)
#pragma unroll
        for (int ct = 0; ct < 8; ++ct) {
#pragma unroll
            for (int r = 0; r < 4; ++r) {
                float p = exp2f(sacc[ct][r]);
                lrow[r] += p;
                Ps[wid * 16 + quad * 4 + r][ct * 16 + l16] = (_Float16)p;
            }
        }

        // O += P @ V  (own Ps rows + shared Vt, all from LDS)
#pragma unroll
        for (int ks = 0; ks < 4; ++ks) {
            f16x8 ap = *(const f16x8*)&Ps[wid * 16 + l16][ks * 32 + quad * 8];
#pragma unroll
            for (int ct = 0; ct < 4; ++ct) {
                f16x8 bv = *(const f16x8*)&Vt[ct * 16 + l16][ks * 32 + quad * 8];
                oacc[ct] = __builtin_amdgcn_mfma_f32_16x16x32_f16(ap, bv, oacc[ct], 0, 0, 0);
            }
        }
        __syncthreads();   // Ks/Vt consumed before next chunk's commit
    }

    // ---- token 1024: rank-1 contribution outside the chunk loop ----
    {
        const _Float16* k1 = kg + (size_t)1024 * QKVC;
        f16x8 kk0 = *(const f16x8*)(k1 + quad * 8);
        f16x8 kk1 = *(const f16x8*)(k1 + 32 + quad * 8);
        float part = 0.f;
#pragma unroll
        for (int j = 0; j < 8; ++j)
            part += (float)aq[0][j] * (float)kk0[j] + (float)aq[1][j] * (float)kk1[j];
        part += __shfl_xor(part, 16);
        part += __shfl_xor(part, 32);   // s' for Q row wid*16 + l16 (replicated over quads)
        float s = part;
        if (q0row == 0 && wid == 0 && l16 == 0) s = row0[c0base + 1024];  // cls row, j=1024
        float p = exp2f(s);
        // add p for row l16 into its owning lrow slot: lane with quad == l16>>2, r == l16&3
#pragma unroll
        for (int r = 0; r < 4; ++r)
            if (quad == (l16 >> 2) && (l16 & 3) == r) lrow[r] += p;
        // O rank-1 update: p_r for row gibase+r lives in lane (quad*4 + r)
        const _Float16* v1 = qg + 2 * DIMC + (size_t)1024 * QKVC;
        float vv[4];
#pragma unroll
        for (int ct = 0; ct < 4; ++ct) vv[ct] = (float)v1[ct * 16 + l16];
#pragma unroll
        for (int r = 0; r < 4; ++r) {
            float pr = __shfl(p, quad * 4 + r);
#pragma unroll
            for (int ct = 0; ct < 4; ++ct) oacc[ct][r] += pr * vv[ct];
        }
    }

    // epilogue: 16-lane reduce of l (exact, no pad correction), store att
#pragma unroll
    for (int r = 0; r < 4; ++r) {
        float l = lrow[r];
#pragma unroll
        for (int off = 1; off < 16; off <<= 1) l += __shfl_xor(l, off);
        int gi = q0row + wid * 16 + quad * 4 + r;
        if (gi >= Nn) continue;
        float inv_l = 1.0f / l;
#pragma unroll
        for (int ct = 0; ct < 4; ++ct) {
            att[((size_t)b * Nn + gi) * DIMC + h * HD + ct * 16 + l16] =
                (_Float16)(oacc[ct][r] * inv_l);
        }
    }
}

extern "C" void kernel_launch(void* const* d_in, const int* in_sizes, int n_in,
                              void* d_out, int out_size, void* d_ws, size_t ws_size,
                              hipStream_t stream) {
    const float* x      = (const float*)d_in[1];
    const int*   xpos   = (const int*)d_in[2];
    const float* w_qkv  = (const float*)d_in[4];
    const float* w_proj = (const float*)d_in[5];
    const float* b_proj = (const float*)d_in[6];
    float* out = (float*)d_out;

    char* ws = (char*)d_ws;
    size_t off = 0;
    auto alloc = [&](size_t bytes) {
        char* p = ws + off;
        off += (bytes + 255) & ~(size_t)255;
        return p;
    };
    _Float16* xh     = (_Float16*)alloc((size_t)MPADA * DIMC * 2);   // padded rows for unguarded staging
    _Float16* qkvh   = (_Float16*)alloc((size_t)MROWS * QKVC * 2);
    _Float16* vt     = (_Float16*)alloc((size_t)Bb * Hh * HD * VNP * 2);
    _Float16* wqkvh  = (_Float16*)alloc((size_t)3 * DIMC * DIMC * 2);
    _Float16* wprojh = (_Float16*)alloc((size_t)DIMC * DIMC * 2);
    float* col0      = (float*)alloc((size_t)Bb * Hh * Nn * 4);
    float* row0      = (float*)alloc((size_t)Bb * Hh * Nn * 4);
    _Float16* atth   = xh;  // alias: x consumed by QKV GEMM before flash writes att

    {
        int n0 = (MROWS * DIMC) / 4;
        int n1 = (3 * DIMC * DIMC) / 4;
        int n2 = (DIMC * DIMC) / 4;
        int nt = n0 + n1 + n2;
        cvt3_kernel<<<(nt + 255) / 256, 256, 0, stream>>>(
            x, xh, n0, w_qkv, wqkvh, n1, w_proj, wprojh, n2);
    }

    // QKV projection -> packed [b,n,3,h,d] (natural GEMM C layout)
    gemm_kernel<0><<<dim3(MPADA / 128, QKVC / 128), 256, 0, stream>>>(
        xh, wqkvh, MROWS, QKVC, DIMC, qkvh, nullptr, nullptr);

    // fused rope (q/k) + V transpose (tokens 0..1023)
    ropevtrans_kernel<<<RBLK + VTBLK, 256, 0, stream>>>(
        qkvh, xpos, col0, row0, vt);

    flash_kernel<<<dim3((Nn + 63) / 64, Bb * Hh), 256, 0, stream>>>(
        qkvh, vt, col0, row0, atth);

    gemm_kernel<1><<<dim3(MPADA / 128, DIMC / 128), 256, 0, stream>>>(
        atth, wprojh, MROWS, DIMC, DIMC, nullptr, b_proj, out);
}